// Round 3
// baseline (318.003 us; speedup 1.0000x reference)
//
#include <hip/hip_runtime.h>
#include <hip/hip_bf16.h>
#include <stdint.h>
#include <stddef.h>

// ---------------------------------------------------------------------------
// RingAttentionLayer on MI355X (gfx950)
// R10: gemm_qkv keeps R9's conflict-free 4-phase schedule, adds:
//  (1) deep prefetch: slices issued 5 phases before their vmcnt (S1(t+1)@ph1,
//      S0(t+2)@ph3, vmcnt(8) at ph2/ph4; 12 loads in flight = m201's depth).
//      Tail issues wrap-around (dead-buffer) batches so vmcnt math stays
//      uniform; vmcnt(0) after loop so no LDS-DMA outlives the block.
//  (2) XCD-aware 1-D grid: m0=(bid&7)*256 -> each XCD owns one A-row-panel
//      (1MB, L2-resident, fetched once); B streams via L3.
// R9 lesson: bank conflicts 4.7M->0 but dur ~flat -> latency-exposed, not
// LDS-throughput-bound. attn_fwd / gemm_o / cvt_all unchanged.
// ---------------------------------------------------------------------------

typedef __attribute__((ext_vector_type(8))) short bf16x8;   // 8 bf16 = 4 VGPRs
typedef __attribute__((ext_vector_type(4))) float f32x4;

#define MFMA_BF16(a, b, c) __builtin_amdgcn_mfma_f32_16x16x32_bf16((a), (b), (c), 0, 0, 0)

__device__ __forceinline__ void load16_lds(const void* g, void* l) {
  __builtin_amdgcn_global_load_lds((const __attribute__((address_space(1))) void*)g,
                                   (__attribute__((address_space(3))) void*)l,
                                   16, 0, 0);
}

__device__ __forceinline__ unsigned short f2bf(float x) {
  union { __hip_bfloat16 b; unsigned short u; } cv;
  cv.b = __float2bfloat16(x);
  return cv.u;
}

// ------------------------------- convert -----------------------------------
__global__ __launch_bounds__(256) void cvt_all(
    const float4* __restrict__ s0, const float4* __restrict__ s1,
    const float4* __restrict__ s2, const float4* __restrict__ s3,
    const float4* __restrict__ s4,
    ushort4* __restrict__ d0, ushort4* __restrict__ d1,
    ushort4* __restrict__ d2, ushort4* __restrict__ d3,
    ushort4* __restrict__ d4) {
  const int seg = blockIdx.x >> 12;
  const int i = ((blockIdx.x & 4095) << 8) + threadIdx.x;
  const float4* s = seg == 0 ? s0 : seg == 1 ? s1 : seg == 2 ? s2 : seg == 3 ? s3 : s4;
  ushort4* d = seg == 0 ? d0 : seg == 1 ? d1 : seg == 2 ? d2 : seg == 3 ? d3 : d4;
  float4 v = s[i];
  ushort4 o;
  o.x = f2bf(v.x); o.y = f2bf(v.y); o.z = f2bf(v.z); o.w = f2bf(v.w);
  d[i] = o;
}

// --------------------------- fused QKV GEMM --------------------------------
// C[2048 x 6144] = A[2048 x 2048] * Bt[6144 x 2048]^T, scatter-epilogue to
// Q(H,S,D) scaled, K(H,S,D), V(H,D,S). 256x256 tile, BK=64 (2 slices of 32),
// 1-D grid 192 (XCD-clustered), 512 threads (8 waves, 2M x 4N).
// LDS slice layout: [128 pairs][8 pos][16B]; logical chunk c (c>>2 = row
// parity, c&3 = 8-col group) lives at pos = c ^ (pair & 7)  (R9, 0-conflict).
__global__ __launch_bounds__(512, 2) void gemm_qkv(
    const unsigned short* __restrict__ A, const unsigned short* __restrict__ Bt,
    const float* __restrict__ qb, const float* __restrict__ kb,
    const float* __restrict__ vb,
    unsigned short* __restrict__ Qo, unsigned short* __restrict__ Ko,
    unsigned short* __restrict__ Vt) {
  // [buf][ks][128 pairs * 64 ushort] = 16KB per slice; 64KB per matrix.
  __shared__ __align__(16) unsigned short sA[2][2][128 * 64];
  __shared__ __align__(16) unsigned short sB[2][2][128 * 64];
  const int tid = threadIdx.x;
  const int wave = tid >> 6, lane = tid & 63;
  const int quad = lane >> 4, l16 = lane & 15;
  const int wr = wave >> 2, wc = wave & 3;       // 2 M-waves x 4 N-waves
  // XCD swizzle: bid%8 -> XCD; give each XCD one m-panel (A L2-resident).
  const int bid = blockIdx.x;
  const int m0 = (bid & 7) << 8, n0 = (bid >> 3) << 8;

  f32x4 acc[8][4] = {};
  bf16x8 af[8], bf01[2], bf23[2];

  // ---- staging geometry (per wave: 2 units x 1024B per slice) ----
  // unit u = rr*8 + wave covers pairs u*8 .. u*8+7. Lane l -> pair_local
  // l>>3, pos l&7; stored logical chunk c = pos ^ (pair&7) = (l&7)^(l>>3).
  const int sc_ = (lane & 7) ^ (lane >> 3);
  const int srow16 = 2 * (lane >> 3) + (sc_ >> 2);  // row within 16-row unit
  const int scol8 = (sc_ & 3) * 8;                  // col elems within slice

  auto stageA = [&](int kt_, int ks_) {
    unsigned short* dst = &sA[kt_ & 1][ks_][wave * 512];
    const unsigned short* src =
        A + (size_t)(m0 + wave * 16 + srow16) * 2048 + kt_ * 64 + ks_ * 32 + scol8;
#pragma unroll
    for (int rr = 0; rr < 2; rr++)
      load16_lds(src + (size_t)rr * 128 * 2048, dst + rr * 4096);
  };
  auto stageB = [&](int kt_, int ks_) {
    unsigned short* dst = &sB[kt_ & 1][ks_][wave * 512];
    const unsigned short* src =
        Bt + (size_t)(n0 + wave * 16 + srow16) * 2048 + kt_ * 64 + ks_ * 32 + scol8;
#pragma unroll
    for (int rr = 0; rr < 2; rr++)
      load16_lds(src + (size_t)rr * 128 * 2048, dst + rr * 4096);
  };

  // ---- frag read addressing ----
  // row = X + l16 (X multiple of 16) -> pair = X/2 + (l16>>1), pair&7 = l16>>1,
  // chunk c = (l16&1)*4 + quad -> pos = c ^ (l16>>1) (lane-constant).
  const int hl = l16 >> 1;
  const int pos8 = ((((l16 & 1) << 2) + quad) ^ hl) << 3;   // ushort offset
  const int aoff = (wr * 64 + hl) * 64 + pos8;   // + mi*512 per mi
  const int boff = (wc * 32 + hl) * 64 + pos8;   // + nj*512 per nj

// one phase: quadrant (K-slice KS, N-frag pair NB..NB+1), 16 MFMA.
#define PHASE(KS, NB, BF, READ_A, STAGE_STMT, VM_STMT)                         \
  {                                                                            \
    const unsigned short* sAp = &sA[kt & 1][KS][aoff];                         \
    const unsigned short* sBp = &sB[kt & 1][KS][boff];                         \
    if (READ_A) {                                                              \
      _Pragma("unroll") for (int mi = 0; mi < 8; mi++)                         \
          af[mi] = *(const bf16x8*)(sAp + mi * 512);                           \
    }                                                                          \
    _Pragma("unroll") for (int j = 0; j < 2; j++)                              \
        BF[j] = *(const bf16x8*)(sBp + (NB + j) * 512);                        \
    STAGE_STMT;                                                                \
    __builtin_amdgcn_s_barrier();                                              \
    asm volatile("s_waitcnt lgkmcnt(0)" ::: "memory");                         \
    __builtin_amdgcn_s_setprio(1);                                             \
    _Pragma("unroll") for (int mi = 0; mi < 8; mi++) {                         \
      acc[mi][NB] = MFMA_BF16(af[mi], BF[0], acc[mi][NB]);                     \
      acc[mi][NB + 1] = MFMA_BF16(af[mi], BF[1], acc[mi][NB + 1]);             \
    }                                                                          \
    __builtin_amdgcn_s_setprio(0);                                             \
    VM_STMT;                                                                   \
    __builtin_amdgcn_s_barrier();                                              \
  }

  // ---- deep-prefetch schedule (12 loads in flight, 5-phase issue->wait) ----
  // ph1(t): read S0(t); issue S1(t+1).   ph2(t): vmcnt(8) -> S1(t) landed.
  // ph3(t): read S1(t); issue S0(t+2).   ph4(t): vmcnt(8) -> S0(t+1) landed.
  // Tail: wrapped (dead-buffer) issues keep vmcnt counts uniform.
  // prologue: S0(0), S1(0), S0(1); wait oldest batch (S0(0)) only.
  stageA(0, 0); stageB(0, 0);   // S0(0)
  stageA(0, 1); stageB(0, 1);   // S1(0)
  stageA(1, 0); stageB(1, 0);   // S0(1)
  asm volatile("s_waitcnt vmcnt(8)" ::: "memory");
  __builtin_amdgcn_s_barrier();

  for (int kt = 0; kt < 32; kt++) {
    const int kn1 = (kt + 1) & 31;   // wrap: tail batches land in dead buffers
    const int kn2 = (kt + 2) & 31;
    // ph1: ks=0, ni 0-1; issue S1(kt+1)
    PHASE(0, 0, bf01, true,  { stageA(kn1, 1); stageB(kn1, 1); }, {});
    // ph2: ks=0, ni 2-3; drain to 8 -> S1(kt) landed (issued 5 phases ago)
    PHASE(0, 2, bf23, false, {},
          { asm volatile("s_waitcnt vmcnt(8)" ::: "memory"); });
    // ph3: ks=1, ni 0-1; issue S0(kt+2)
    PHASE(1, 0, bf01, true,  { stageA(kn2, 0); stageB(kn2, 0); }, {});
    // ph4: ks=1, ni 2-3; drain to 8 -> S0(kt+1) landed
    PHASE(1, 2, bf23, false, {},
          { asm volatile("s_waitcnt vmcnt(8)" ::: "memory"); });
  }
#undef PHASE
  // no LDS-DMA may outlive this block (next block reuses our LDS space).
  asm volatile("s_waitcnt vmcnt(0)" ::: "memory");

  const float qscale = 0.088388347648318447f * 1.4426950408889634f;  // scale*log2e
#pragma unroll
  for (int mi = 0; mi < 8; mi++) {
    const int row = m0 + wr * 128 + mi * 16 + quad * 4;
#pragma unroll
    for (int ni = 0; ni < 4; ni++) {
      const int col = n0 + wc * 64 + ni * 16 + l16;
#pragma unroll
      for (int r = 0; r < 4; r++) {
        const float v = acc[mi][ni][r];
        const int rr = row + r;
        if (col < 2048) {
          const int hh = col >> 7, d = col & 127;
          Qo[((size_t)hh * 2048 + rr) * 128 + d] = f2bf((v + qb[col]) * qscale);
        } else if (col < 4096) {
          const int f = col - 2048;
          const int hh = f >> 7, d = f & 127;
          Ko[((size_t)hh * 2048 + rr) * 128 + d] = f2bf(v + kb[f]);
        } else {
          const int f = col - 4096;
          const int hh = f >> 7, d = f & 127;
          Vt[((size_t)hh * 128 + d) * 2048 + rr] = f2bf(v + vb[f]);  // (H,D,S)
        }
      }
    }
  }
}

// ------------------------------ attention ----------------------------------
// grid (32 qtiles, 16 heads) = 512 blocks, block = 256 threads (4 waves),
// 72KB LDS -> exactly 2 blocks/CU = 8 waves/CU = 2 waves/SIMD. Each wave owns
// 16 q. K/V double-buffered (stage kt+1 after the barrier draining stage kt).
// Transposed-score softmax (lane-private + 2 shfl), dual accumulators with
// masked fork at kt==qt, in-register ring combine.
__global__ __launch_bounds__(256, 2) void attn_fwd(
    const unsigned short* __restrict__ Q, const unsigned short* __restrict__ K,
    const unsigned short* __restrict__ V,   // (H, D, S) transposed
    unsigned short* __restrict__ O,         // (S, H*D) bf16
    const int* __restrict__ wsp) {
  const int qt = blockIdx.x, h = blockIdx.y;
  const int tid = threadIdx.x;
  const int wave = tid >> 6, lane = tid & 63;
  const int quad = lane >> 4, l16 = lane & 15;

  __shared__ __align__(16) unsigned short sK0[64 * 128];  // Q staged here first
  __shared__ __align__(16) unsigned short sK1[64 * 128];
  __shared__ __align__(16) unsigned short sV0[128 * 64];
  __shared__ __align__(16) unsigned short sV1[128 * 64];
  __shared__ __align__(16) unsigned short sP[4][16 * 64];

  const unsigned short* Qh = Q + (size_t)h * 2048 * 128;
  const unsigned short* Kh = K + (size_t)h * 2048 * 128;
  const unsigned short* Vh = V + (size_t)h * 128 * 2048;
  unsigned short* sPw = sP[wave];

  // stage Q tile [64][128] into sK0, chunk swizzle blk ^ (row&15)
  for (int c = wave; c < 16; c += 4) {
    const int rowc = lane >> 4;
    const int row = c * 4 + rowc;
    const int blk = (lane & 15) ^ (row & 15);
    load16_lds(Qh + (size_t)(qt * 64 + row) * 128 + blk * 8, &sK0[c * 512]);
  }
  __syncthreads();

  bf16x8 qf[4];
#pragma unroll
  for (int ds = 0; ds < 4; ds++)
    qf[ds] = *(const bf16x8*)&sK0[(wave * 16 + l16) * 128 + (((ds * 4 + quad) ^ l16) << 3)];
  __syncthreads();  // all waves hold Q frags before K0 overwrites sK0

  float m1 = -3.0e38f, l1 = 0.f, m2 = -3.0e38f, l2 = 0.f;
  f32x4 o1[8], o2[8];
#pragma unroll
  for (int j = 0; j < 8; j++) { o1[j] = f32x4{0.f, 0.f, 0.f, 0.f}; o2[j] = f32x4{0.f, 0.f, 0.f, 0.f}; }

  auto stageKV = [&](int kt, unsigned short* kDst, unsigned short* vDst) {
    const int k0 = kt << 6;
    for (int c = wave; c < 16; c += 4) {
      {  // K tile [64 k][128 d]
        const int rowc = lane >> 4;
        const int row = c * 4 + rowc;
        const int blk = (lane & 15) ^ (row & 15);
        load16_lds(Kh + (size_t)(k0 + row) * 128 + blk * 8, &kDst[c * 512]);
      }
      {  // V tile [128 d][64 k]
        const int rowc = lane >> 3;
        const int row = c * 8 + rowc;
        const int blk = (lane & 7) ^ (rowc & 7);
        load16_lds(Vh + (size_t)row * 2048 + k0 + blk * 8, &vDst[c * 512]);
      }
    }
  };

  auto softmax_update = [&](float& m, float& l, f32x4 (&o)[8],
                            const f32x4 (&stt)[4], bool masked, int k0) {
    const int qg = qt * 64 + wave * 16 + l16;  // this lane's q column
    float t[4][4];
    float mx = -3.0e38f;
#pragma unroll
    for (int ni = 0; ni < 4; ni++)
#pragma unroll
      for (int r = 0; r < 4; r++) {
        float v = stt[ni][r];
        if (masked && (k0 + ni * 16 + quad * 4 + r > qg)) v = -3.0e38f;
        t[ni][r] = v;
        mx = fmaxf(mx, v);
      }
    mx = fmaxf(mx, __shfl_xor(mx, 16));
    mx = fmaxf(mx, __shfl_xor(mx, 32));
    const float mn = fmaxf(m, mx);
    const float al = exp2f(m - mn);
    float rs = 0.f;
#pragma unroll
    for (int ni = 0; ni < 4; ni++) {
      union { unsigned short u[4]; uint2 v; } pk;
#pragma unroll
      for (int r = 0; r < 4; r++) {
        const float p = exp2f(t[ni][r] - mn);
        rs += p;
        pk.u[r] = f2bf(p);
      }
      const int off =
          l16 * 64 + (((ni * 2 + (quad >> 1)) ^ (l16 & 7)) << 3) + ((quad & 1) << 2);
      *(uint2*)&sPw[off] = pk.v;
    }
    rs += __shfl_xor(rs, 16);
    rs += __shfl_xor(rs, 32);
    const bool grew = !__all(mn == m);
    l = l * al + rs;
    m = mn;
    if (grew) {  // wave-uniform: skip o-rescale when no lane's max moved
#pragma unroll
      for (int r = 0; r < 4; r++) {
        const int src = (lane & 48) + quad * 4 + r;  // same quad, l16 = quad*4+r
        const float ab = __shfl(al, src);
#pragma unroll
        for (int j = 0; j < 8; j++) o[j][r] *= ab;
      }
    }
  };

  auto pv = [&](f32x4 (&o)[8], const unsigned short* vBuf) {
#pragma unroll
    for (int ks = 0; ks < 2; ks++) {
      const int cs = (((ks * 4 + quad) ^ (l16 & 7)) << 3);
      const bf16x8 pf = *(const bf16x8*)&sPw[l16 * 64 + cs];
#pragma unroll
      for (int j = 0; j < 8; j++) {
        const bf16x8 vf = *(const bf16x8*)&vBuf[(j * 16 + l16) * 64 + cs];
        o[j] = MFMA_BF16(pf, vf, o[j]);
      }
    }
  };

  auto compute_tile = [&](int kt, const unsigned short* kBuf,
                          const unsigned short* vBuf) {
    const int k0 = kt << 6;
    f32x4 st[4];
#pragma unroll
    for (int ni = 0; ni < 4; ni++) st[ni] = f32x4{0.f, 0.f, 0.f, 0.f};
#pragma unroll
    for (int ds = 0; ds < 4; ds++) {
#pragma unroll
      for (int ni = 0; ni < 4; ni++) {
        const bf16x8 kf =
            *(const bf16x8*)&kBuf[(ni * 16 + l16) * 128 + (((ds * 4 + quad) ^ l16) << 3)];
        st[ni] = MFMA_BF16(kf, qf[ds], st[ni]);
      }
    }

    if (kt == qt) {  // diagonal: fork masked stats, dual update
      m1 = m2; l1 = l2;
#pragma unroll
      for (int j = 0; j < 8; j++) o1[j] = o2[j];
      softmax_update(m1, l1, o1, st, true, k0);
      pv(o1, vBuf);
    }
    softmax_update(m2, l2, o2, st, false, k0);
    pv(o2, vBuf);
  };

  // pipelined K-loop: stage(kt+1) issues right after the barrier that
  // drained stage(kt); compute(kt) hides the latency.
  stageKV(0, sK0, sV0);
  for (int kt2 = 0; kt2 < 32; kt2 += 2) {
    __syncthreads();                       // drains stage(kt2) [buf0]
    if (kt2 + 1 < 32) stageKV(kt2 + 1, sK1, sV1);
    compute_tile(kt2, sK0, sV0);
    __syncthreads();                       // drains stage(kt2+1) [buf1]
    if (kt2 + 2 < 32) stageKV(kt2 + 2, sK0, sV0);
    compute_tile(kt2 + 1, sK1, sV1);
  }

  // in-register ring combine: 1x masked + (ws-1)x unmasked (log2 domain)
  const float fws = (float)(wsp[0] - 1);
  const float a = exp2f(m1 - m2);
  const float se = l1 * a + fws * l2;
  const float inv = 1.0f / (se + 1e-8f);
  const float f1 = (a / (l1 + 1e-8f)) * inv;
  const float f2 = (fws / (l2 + 1e-8f)) * inv;
#pragma unroll
  for (int r = 0; r < 4; r++) {
    const int src = (lane & 48) + quad * 4 + r;  // same quad, l16 = quad*4+r
    const float f1b = __shfl(f1, src);
    const float f2b = __shfl(f2, src);
    const int row = qt * 64 + wave * 16 + quad * 4 + r;
#pragma unroll
    for (int j = 0; j < 8; j++) {
      const float ov = o1[j][r] * f1b + o2[j][r] * f2b;
      O[(size_t)row * 2048 + h * 128 + j * 16 + l16] = f2bf(ov);
    }
  }
}

// ------------------------------ O-proj GEMM --------------------------------
// out[2048 x 2048] fp32 = attn[2048 x 2048]bf16 * ow[2048 x 2048]^T + ob
// 64x128 tile, BK=128 (16 iters), chunk-XOR swizzle on 16-chunk rows.
__global__ __launch_bounds__(256) void gemm_o(
    const unsigned short* __restrict__ A, const unsigned short* __restrict__ Bt,
    const float* __restrict__ ob, float* __restrict__ Cout) {
  __shared__ __align__(16) unsigned short sA[64 * 128];
  __shared__ __align__(16) unsigned short sB[128 * 128];
  const int tid = threadIdx.x;
  const int wave = tid >> 6, lane = tid & 63;
  const int quad = lane >> 4, l16 = lane & 15;
  const int wm = wave >> 1, wn = wave & 1;
  const int m0 = blockIdx.y << 6, n0 = blockIdx.x << 7;

  f32x4 acc[2][4] = {};

  for (int k0 = 0; k0 < 2048; k0 += 128) {
    __syncthreads();
#pragma unroll
    for (int t = 0; t < 4; t++) {
      const int i = t * 4 + wave;
      const int idx = i * 64 + lane;
      const int row = idx >> 4;
      const int c = (idx & 15) ^ (row & 15);
      load16_lds(A + (size_t)(m0 + row) * 2048 + k0 + c * 8, &sA[i * 512]);
    }
#pragma unroll
    for (int t = 0; t < 8; t++) {
      const int i = t * 4 + wave;
      const int idx = i * 64 + lane;
      const int row = idx >> 4;
      const int c = (idx & 15) ^ (row & 15);
      load16_lds(Bt + (size_t)(n0 + row) * 2048 + k0 + c * 8, &sB[i * 512]);
    }
    __syncthreads();
#pragma unroll
    for (int ks = 0; ks < 4; ks++) {
      const int cs = ((ks * 4 + quad) ^ l16) << 3;
      bf16x8 af[2], bfr[4];
#pragma unroll
      for (int i = 0; i < 2; i++)
        af[i] = *(const bf16x8*)&sA[(wm * 32 + i * 16 + l16) * 128 + cs];
#pragma unroll
      for (int i = 0; i < 4; i++)
        bfr[i] = *(const bf16x8*)&sB[(wn * 64 + i * 16 + l16) * 128 + cs];
#pragma unroll
      for (int mi = 0; mi < 2; mi++)
#pragma unroll
        for (int ni = 0; ni < 4; ni++)
          acc[mi][ni] = MFMA_BF16(af[mi], bfr[ni], acc[mi][ni]);
    }
  }

#pragma unroll
  for (int mi = 0; mi < 2; mi++) {
    const int row = m0 + wm * 32 + mi * 16 + quad * 4;
#pragma unroll
    for (int ni = 0; ni < 4; ni++) {
      const int col = n0 + wn * 64 + ni * 16 + l16;
#pragma unroll
      for (int r = 0; r < 4; r++) {
        Cout[(size_t)(row + r) * 2048 + col] = acc[mi][ni][r] + ob[col];
      }
    }
  }
}

// ------------------------------- launcher ----------------------------------
extern "C" void kernel_launch(void* const* d_in, const int* in_sizes, int n_in,
                              void* d_out, int out_size, void* d_ws, size_t ws_size,
                              hipStream_t stream) {
  (void)in_sizes; (void)n_in; (void)out_size; (void)ws_size;
  const float* hs = (const float*)d_in[0];
  const float* qw = (const float*)d_in[1];
  const float* qb = (const float*)d_in[2];
  const float* kw = (const float*)d_in[3];
  const float* kb = (const float*)d_in[4];
  const float* vw = (const float*)d_in[5];
  const float* vb = (const float*)d_in[6];
  const float* ow = (const float*)d_in[7];
  const float* ob = (const float*)d_in[8];
  const int* wsz = (const int*)d_in[9];

  char* w = (char*)d_ws;
  unsigned short* hsb  = (unsigned short*)(w + 0);          //  8 MB (S,HID) bf16
  unsigned short* wqkv = (unsigned short*)(w + 8388608);    // 24 MB (6144,2048) bf16
  unsigned short* owb  = (unsigned short*)(w + 33554432);   //  8 MB
  unsigned short* Qb_  = (unsigned short*)(w + 41943040);   //  8 MB (H,S,D)
  unsigned short* Kb_  = (unsigned short*)(w + 50331648);   //  8 MB (H,S,D)
  unsigned short* Vtb  = (unsigned short*)(w + 58720256);   //  8 MB (H,D,S)
  unsigned short* atb  = (unsigned short*)(w + 67108864);   //  8 MB (S,H*D)

  cvt_all<<<20480, 256, 0, stream>>>(
      (const float4*)hs, (const float4*)qw, (const float4*)kw, (const float4*)vw,
      (const float4*)ow,
      (ushort4*)hsb, (ushort4*)wqkv, (ushort4*)(wqkv + 4194304),
      (ushort4*)(wqkv + 8388608), (ushort4*)owb);

  gemm_qkv<<<192, 512, 0, stream>>>(hsb, wqkv, qb, kb, vb, Qb_, Kb_, Vtb);
  attn_fwd<<<dim3(32, 16), 256, 0, stream>>>(Qb_, Kb_, Vtb, atb, wsz);
  gemm_o<<<dim3(16, 32), 256, 0, stream>>>(atb, owb, ob, (float*)d_out);
}

// Round 4
// 317.353 us; speedup vs baseline: 1.0020x; 1.0020x over previous
//
#include <hip/hip_runtime.h>
#include <hip/hip_bf16.h>
#include <stdint.h>
#include <stddef.h>

// ---------------------------------------------------------------------------
// RingAttentionLayer on MI355X (gfx950)
// R11: isolate the prefetch-depth lever. R10 bundled deep prefetch (12 loads
// in flight, 5-phase issue->wait) with an XCD grid swizzle; counters showed
// the swizzle DOUBLED fetch (each XCD got 24 distinct B-panels concurrently
// -> L2 useless for B). R11 = R10's deep-prefetch schedule + R9's natural
// (24,8) grid. Single variable vs R9 = depth.
// attn_fwd / gemm_o / cvt_all unchanged.
// ---------------------------------------------------------------------------

typedef __attribute__((ext_vector_type(8))) short bf16x8;   // 8 bf16 = 4 VGPRs
typedef __attribute__((ext_vector_type(4))) float f32x4;

#define MFMA_BF16(a, b, c) __builtin_amdgcn_mfma_f32_16x16x32_bf16((a), (b), (c), 0, 0, 0)

__device__ __forceinline__ void load16_lds(const void* g, void* l) {
  __builtin_amdgcn_global_load_lds((const __attribute__((address_space(1))) void*)g,
                                   (__attribute__((address_space(3))) void*)l,
                                   16, 0, 0);
}

__device__ __forceinline__ unsigned short f2bf(float x) {
  union { __hip_bfloat16 b; unsigned short u; } cv;
  cv.b = __float2bfloat16(x);
  return cv.u;
}

// ------------------------------- convert -----------------------------------
__global__ __launch_bounds__(256) void cvt_all(
    const float4* __restrict__ s0, const float4* __restrict__ s1,
    const float4* __restrict__ s2, const float4* __restrict__ s3,
    const float4* __restrict__ s4,
    ushort4* __restrict__ d0, ushort4* __restrict__ d1,
    ushort4* __restrict__ d2, ushort4* __restrict__ d3,
    ushort4* __restrict__ d4) {
  const int seg = blockIdx.x >> 12;
  const int i = ((blockIdx.x & 4095) << 8) + threadIdx.x;
  const float4* s = seg == 0 ? s0 : seg == 1 ? s1 : seg == 2 ? s2 : seg == 3 ? s3 : s4;
  ushort4* d = seg == 0 ? d0 : seg == 1 ? d1 : seg == 2 ? d2 : seg == 3 ? d3 : d4;
  float4 v = s[i];
  ushort4 o;
  o.x = f2bf(v.x); o.y = f2bf(v.y); o.z = f2bf(v.z); o.w = f2bf(v.w);
  d[i] = o;
}

// --------------------------- fused QKV GEMM --------------------------------
// C[2048 x 6144] = A[2048 x 2048] * Bt[6144 x 2048]^T, scatter-epilogue to
// Q(H,S,D) scaled, K(H,S,D), V(H,D,S). 256x256 tile, BK=64 (2 slices of 32),
// grid (24,8), 512 threads (8 waves, 2M x 4N).
// LDS slice layout: [128 pairs][8 pos][16B]; logical chunk c (c>>2 = row
// parity, c&3 = 8-col group) lives at pos = c ^ (pair & 7)  (R9, 0-conflict).
__global__ __launch_bounds__(512, 2) void gemm_qkv(
    const unsigned short* __restrict__ A, const unsigned short* __restrict__ Bt,
    const float* __restrict__ qb, const float* __restrict__ kb,
    const float* __restrict__ vb,
    unsigned short* __restrict__ Qo, unsigned short* __restrict__ Ko,
    unsigned short* __restrict__ Vt) {
  // [buf][ks][128 pairs * 64 ushort] = 16KB per slice; 64KB per matrix.
  __shared__ __align__(16) unsigned short sA[2][2][128 * 64];
  __shared__ __align__(16) unsigned short sB[2][2][128 * 64];
  const int tid = threadIdx.x;
  const int wave = tid >> 6, lane = tid & 63;
  const int quad = lane >> 4, l16 = lane & 15;
  const int wr = wave >> 2, wc = wave & 3;       // 2 M-waves x 4 N-waves
  const int m0 = blockIdx.y << 8, n0 = blockIdx.x << 8;

  f32x4 acc[8][4] = {};
  bf16x8 af[8], bf01[2], bf23[2];

  // ---- staging geometry (per wave: 2 units x 1024B per slice) ----
  // unit u = rr*8 + wave covers pairs u*8 .. u*8+7. Lane l -> pair_local
  // l>>3, pos l&7; stored logical chunk c = pos ^ (pair&7) = (l&7)^(l>>3).
  const int sc_ = (lane & 7) ^ (lane >> 3);
  const int srow16 = 2 * (lane >> 3) + (sc_ >> 2);  // row within 16-row unit
  const int scol8 = (sc_ & 3) * 8;                  // col elems within slice

  auto stageA = [&](int kt_, int ks_) {
    unsigned short* dst = &sA[kt_ & 1][ks_][wave * 512];
    const unsigned short* src =
        A + (size_t)(m0 + wave * 16 + srow16) * 2048 + kt_ * 64 + ks_ * 32 + scol8;
#pragma unroll
    for (int rr = 0; rr < 2; rr++)
      load16_lds(src + (size_t)rr * 128 * 2048, dst + rr * 4096);
  };
  auto stageB = [&](int kt_, int ks_) {
    unsigned short* dst = &sB[kt_ & 1][ks_][wave * 512];
    const unsigned short* src =
        Bt + (size_t)(n0 + wave * 16 + srow16) * 2048 + kt_ * 64 + ks_ * 32 + scol8;
#pragma unroll
    for (int rr = 0; rr < 2; rr++)
      load16_lds(src + (size_t)rr * 128 * 2048, dst + rr * 4096);
  };

  // ---- frag read addressing ----
  // row = X + l16 (X multiple of 16) -> pair = X/2 + (l16>>1), pair&7 = l16>>1,
  // chunk c = (l16&1)*4 + quad -> pos = c ^ (l16>>1) (lane-constant).
  const int hl = l16 >> 1;
  const int pos8 = ((((l16 & 1) << 2) + quad) ^ hl) << 3;   // ushort offset
  const int aoff = (wr * 64 + hl) * 64 + pos8;   // + mi*512 per mi
  const int boff = (wc * 32 + hl) * 64 + pos8;   // + nj*512 per nj

// one phase: quadrant (K-slice KS, N-frag pair NB..NB+1), 16 MFMA.
#define PHASE(KS, NB, BF, READ_A, STAGE_STMT, VM_STMT)                         \
  {                                                                            \
    const unsigned short* sAp = &sA[kt & 1][KS][aoff];                         \
    const unsigned short* sBp = &sB[kt & 1][KS][boff];                         \
    if (READ_A) {                                                              \
      _Pragma("unroll") for (int mi = 0; mi < 8; mi++)                         \
          af[mi] = *(const bf16x8*)(sAp + mi * 512);                           \
    }                                                                          \
    _Pragma("unroll") for (int j = 0; j < 2; j++)                              \
        BF[j] = *(const bf16x8*)(sBp + (NB + j) * 512);                        \
    STAGE_STMT;                                                                \
    __builtin_amdgcn_s_barrier();                                              \
    asm volatile("s_waitcnt lgkmcnt(0)" ::: "memory");                         \
    __builtin_amdgcn_s_setprio(1);                                             \
    _Pragma("unroll") for (int mi = 0; mi < 8; mi++) {                         \
      acc[mi][NB] = MFMA_BF16(af[mi], BF[0], acc[mi][NB]);                     \
      acc[mi][NB + 1] = MFMA_BF16(af[mi], BF[1], acc[mi][NB + 1]);             \
    }                                                                          \
    __builtin_amdgcn_s_setprio(0);                                             \
    VM_STMT;                                                                   \
    __builtin_amdgcn_s_barrier();                                              \
  }

  // ---- deep-prefetch schedule (12 loads in flight, 5-phase issue->wait) ----
  // ph1(t): read S0(t); issue S1(t+1).   ph2(t): vmcnt(8) -> S1(t) landed.
  // ph3(t): read S1(t); issue S0(t+2).   ph4(t): vmcnt(8) -> S0(t+1) landed.
  // Tail: wrapped (dead-buffer) issues keep vmcnt counts uniform.
  // prologue: S0(0), S1(0), S0(1); wait oldest batch (S0(0)) only.
  stageA(0, 0); stageB(0, 0);   // S0(0)
  stageA(0, 1); stageB(0, 1);   // S1(0)
  stageA(1, 0); stageB(1, 0);   // S0(1)
  asm volatile("s_waitcnt vmcnt(8)" ::: "memory");
  __builtin_amdgcn_s_barrier();

  for (int kt = 0; kt < 32; kt++) {
    const int kn1 = (kt + 1) & 31;   // wrap: tail batches land in dead buffers
    const int kn2 = (kt + 2) & 31;
    // ph1: ks=0, ni 0-1; issue S1(kt+1)
    PHASE(0, 0, bf01, true,  { stageA(kn1, 1); stageB(kn1, 1); }, {});
    // ph2: ks=0, ni 2-3; drain to 8 -> S1(kt) landed (issued 5 phases ago)
    PHASE(0, 2, bf23, false, {},
          { asm volatile("s_waitcnt vmcnt(8)" ::: "memory"); });
    // ph3: ks=1, ni 0-1; issue S0(kt+2)
    PHASE(1, 0, bf01, true,  { stageA(kn2, 0); stageB(kn2, 0); }, {});
    // ph4: ks=1, ni 2-3; drain to 8 -> S0(kt+1) landed
    PHASE(1, 2, bf23, false, {},
          { asm volatile("s_waitcnt vmcnt(8)" ::: "memory"); });
  }
#undef PHASE
  // no LDS-DMA may outlive this block (next block reuses our LDS space).
  asm volatile("s_waitcnt vmcnt(0)" ::: "memory");

  const float qscale = 0.088388347648318447f * 1.4426950408889634f;  // scale*log2e
#pragma unroll
  for (int mi = 0; mi < 8; mi++) {
    const int row = m0 + wr * 128 + mi * 16 + quad * 4;
#pragma unroll
    for (int ni = 0; ni < 4; ni++) {
      const int col = n0 + wc * 64 + ni * 16 + l16;
#pragma unroll
      for (int r = 0; r < 4; r++) {
        const float v = acc[mi][ni][r];
        const int rr = row + r;
        if (col < 2048) {
          const int hh = col >> 7, d = col & 127;
          Qo[((size_t)hh * 2048 + rr) * 128 + d] = f2bf((v + qb[col]) * qscale);
        } else if (col < 4096) {
          const int f = col - 2048;
          const int hh = f >> 7, d = f & 127;
          Ko[((size_t)hh * 2048 + rr) * 128 + d] = f2bf(v + kb[f]);
        } else {
          const int f = col - 4096;
          const int hh = f >> 7, d = f & 127;
          Vt[((size_t)hh * 128 + d) * 2048 + rr] = f2bf(v + vb[f]);  // (H,D,S)
        }
      }
    }
  }
}

// ------------------------------ attention ----------------------------------
// grid (32 qtiles, 16 heads) = 512 blocks, block = 256 threads (4 waves),
// 72KB LDS -> exactly 2 blocks/CU = 8 waves/CU = 2 waves/SIMD. Each wave owns
// 16 q. K/V double-buffered (stage kt+1 after the barrier draining stage kt).
// Transposed-score softmax (lane-private + 2 shfl), dual accumulators with
// masked fork at kt==qt, in-register ring combine.
__global__ __launch_bounds__(256, 2) void attn_fwd(
    const unsigned short* __restrict__ Q, const unsigned short* __restrict__ K,
    const unsigned short* __restrict__ V,   // (H, D, S) transposed
    unsigned short* __restrict__ O,         // (S, H*D) bf16
    const int* __restrict__ wsp) {
  const int qt = blockIdx.x, h = blockIdx.y;
  const int tid = threadIdx.x;
  const int wave = tid >> 6, lane = tid & 63;
  const int quad = lane >> 4, l16 = lane & 15;

  __shared__ __align__(16) unsigned short sK0[64 * 128];  // Q staged here first
  __shared__ __align__(16) unsigned short sK1[64 * 128];
  __shared__ __align__(16) unsigned short sV0[128 * 64];
  __shared__ __align__(16) unsigned short sV1[128 * 64];
  __shared__ __align__(16) unsigned short sP[4][16 * 64];

  const unsigned short* Qh = Q + (size_t)h * 2048 * 128;
  const unsigned short* Kh = K + (size_t)h * 2048 * 128;
  const unsigned short* Vh = V + (size_t)h * 128 * 2048;
  unsigned short* sPw = sP[wave];

  // stage Q tile [64][128] into sK0, chunk swizzle blk ^ (row&15)
  for (int c = wave; c < 16; c += 4) {
    const int rowc = lane >> 4;
    const int row = c * 4 + rowc;
    const int blk = (lane & 15) ^ (row & 15);
    load16_lds(Qh + (size_t)(qt * 64 + row) * 128 + blk * 8, &sK0[c * 512]);
  }
  __syncthreads();

  bf16x8 qf[4];
#pragma unroll
  for (int ds = 0; ds < 4; ds++)
    qf[ds] = *(const bf16x8*)&sK0[(wave * 16 + l16) * 128 + (((ds * 4 + quad) ^ l16) << 3)];
  __syncthreads();  // all waves hold Q frags before K0 overwrites sK0

  float m1 = -3.0e38f, l1 = 0.f, m2 = -3.0e38f, l2 = 0.f;
  f32x4 o1[8], o2[8];
#pragma unroll
  for (int j = 0; j < 8; j++) { o1[j] = f32x4{0.f, 0.f, 0.f, 0.f}; o2[j] = f32x4{0.f, 0.f, 0.f, 0.f}; }

  auto stageKV = [&](int kt, unsigned short* kDst, unsigned short* vDst) {
    const int k0 = kt << 6;
    for (int c = wave; c < 16; c += 4) {
      {  // K tile [64 k][128 d]
        const int rowc = lane >> 4;
        const int row = c * 4 + rowc;
        const int blk = (lane & 15) ^ (row & 15);
        load16_lds(Kh + (size_t)(k0 + row) * 128 + blk * 8, &kDst[c * 512]);
      }
      {  // V tile [128 d][64 k]
        const int rowc = lane >> 3;
        const int row = c * 8 + rowc;
        const int blk = (lane & 7) ^ (rowc & 7);
        load16_lds(Vh + (size_t)row * 2048 + k0 + blk * 8, &vDst[c * 512]);
      }
    }
  };

  auto softmax_update = [&](float& m, float& l, f32x4 (&o)[8],
                            const f32x4 (&stt)[4], bool masked, int k0) {
    const int qg = qt * 64 + wave * 16 + l16;  // this lane's q column
    float t[4][4];
    float mx = -3.0e38f;
#pragma unroll
    for (int ni = 0; ni < 4; ni++)
#pragma unroll
      for (int r = 0; r < 4; r++) {
        float v = stt[ni][r];
        if (masked && (k0 + ni * 16 + quad * 4 + r > qg)) v = -3.0e38f;
        t[ni][r] = v;
        mx = fmaxf(mx, v);
      }
    mx = fmaxf(mx, __shfl_xor(mx, 16));
    mx = fmaxf(mx, __shfl_xor(mx, 32));
    const float mn = fmaxf(m, mx);
    const float al = exp2f(m - mn);
    float rs = 0.f;
#pragma unroll
    for (int ni = 0; ni < 4; ni++) {
      union { unsigned short u[4]; uint2 v; } pk;
#pragma unroll
      for (int r = 0; r < 4; r++) {
        const float p = exp2f(t[ni][r] - mn);
        rs += p;
        pk.u[r] = f2bf(p);
      }
      const int off =
          l16 * 64 + (((ni * 2 + (quad >> 1)) ^ (l16 & 7)) << 3) + ((quad & 1) << 2);
      *(uint2*)&sPw[off] = pk.v;
    }
    rs += __shfl_xor(rs, 16);
    rs += __shfl_xor(rs, 32);
    const bool grew = !__all(mn == m);
    l = l * al + rs;
    m = mn;
    if (grew) {  // wave-uniform: skip o-rescale when no lane's max moved
#pragma unroll
      for (int r = 0; r < 4; r++) {
        const int src = (lane & 48) + quad * 4 + r;  // same quad, l16 = quad*4+r
        const float ab = __shfl(al, src);
#pragma unroll
        for (int j = 0; j < 8; j++) o[j][r] *= ab;
      }
    }
  };

  auto pv = [&](f32x4 (&o)[8], const unsigned short* vBuf) {
#pragma unroll
    for (int ks = 0; ks < 2; ks++) {
      const int cs = (((ks * 4 + quad) ^ (l16 & 7)) << 3);
      const bf16x8 pf = *(const bf16x8*)&sPw[l16 * 64 + cs];
#pragma unroll
      for (int j = 0; j < 8; j++) {
        const bf16x8 vf = *(const bf16x8*)&vBuf[(j * 16 + l16) * 64 + cs];
        o[j] = MFMA_BF16(pf, vf, o[j]);
      }
    }
  };

  auto compute_tile = [&](int kt, const unsigned short* kBuf,
                          const unsigned short* vBuf) {
    const int k0 = kt << 6;
    f32x4 st[4];
#pragma unroll
    for (int ni = 0; ni < 4; ni++) st[ni] = f32x4{0.f, 0.f, 0.f, 0.f};
#pragma unroll
    for (int ds = 0; ds < 4; ds++) {
#pragma unroll
      for (int ni = 0; ni < 4; ni++) {
        const bf16x8 kf =
            *(const bf16x8*)&kBuf[(ni * 16 + l16) * 128 + (((ds * 4 + quad) ^ l16) << 3)];
        st[ni] = MFMA_BF16(kf, qf[ds], st[ni]);
      }
    }

    if (kt == qt) {  // diagonal: fork masked stats, dual update
      m1 = m2; l1 = l2;
#pragma unroll
      for (int j = 0; j < 8; j++) o1[j] = o2[j];
      softmax_update(m1, l1, o1, st, true, k0);
      pv(o1, vBuf);
    }
    softmax_update(m2, l2, o2, st, false, k0);
    pv(o2, vBuf);
  };

  // pipelined K-loop: stage(kt+1) issues right after the barrier that
  // drained stage(kt); compute(kt) hides the latency.
  stageKV(0, sK0, sV0);
  for (int kt2 = 0; kt2 < 32; kt2 += 2) {
    __syncthreads();                       // drains stage(kt2) [buf0]
    if (kt2 + 1 < 32) stageKV(kt2 + 1, sK1, sV1);
    compute_tile(kt2, sK0, sV0);
    __syncthreads();                       // drains stage(kt2+1) [buf1]
    if (kt2 + 2 < 32) stageKV(kt2 + 2, sK0, sV0);
    compute_tile(kt2 + 1, sK1, sV1);
  }

  // in-register ring combine: 1x masked + (ws-1)x unmasked (log2 domain)
  const float fws = (float)(wsp[0] - 1);
  const float a = exp2f(m1 - m2);
  const float se = l1 * a + fws * l2;
  const float inv = 1.0f / (se + 1e-8f);
  const float f1 = (a / (l1 + 1e-8f)) * inv;
  const float f2 = (fws / (l2 + 1e-8f)) * inv;
#pragma unroll
  for (int r = 0; r < 4; r++) {
    const int src = (lane & 48) + quad * 4 + r;  // same quad, l16 = quad*4+r
    const float f1b = __shfl(f1, src);
    const float f2b = __shfl(f2, src);
    const int row = qt * 64 + wave * 16 + quad * 4 + r;
#pragma unroll
    for (int j = 0; j < 8; j++) {
      const float ov = o1[j][r] * f1b + o2[j][r] * f2b;
      O[(size_t)row * 2048 + h * 128 + j * 16 + l16] = f2bf(ov);
    }
  }
}

// ------------------------------ O-proj GEMM --------------------------------
// out[2048 x 2048] fp32 = attn[2048 x 2048]bf16 * ow[2048 x 2048]^T + ob
// 64x128 tile, BK=128 (16 iters), chunk-XOR swizzle on 16-chunk rows.
__global__ __launch_bounds__(256) void gemm_o(
    const unsigned short* __restrict__ A, const unsigned short* __restrict__ Bt,
    const float* __restrict__ ob, float* __restrict__ Cout) {
  __shared__ __align__(16) unsigned short sA[64 * 128];
  __shared__ __align__(16) unsigned short sB[128 * 128];
  const int tid = threadIdx.x;
  const int wave = tid >> 6, lane = tid & 63;
  const int quad = lane >> 4, l16 = lane & 15;
  const int wm = wave >> 1, wn = wave & 1;
  const int m0 = blockIdx.y << 6, n0 = blockIdx.x << 7;

  f32x4 acc[2][4] = {};

  for (int k0 = 0; k0 < 2048; k0 += 128) {
    __syncthreads();
#pragma unroll
    for (int t = 0; t < 4; t++) {
      const int i = t * 4 + wave;
      const int idx = i * 64 + lane;
      const int row = idx >> 4;
      const int c = (idx & 15) ^ (row & 15);
      load16_lds(A + (size_t)(m0 + row) * 2048 + k0 + c * 8, &sA[i * 512]);
    }
#pragma unroll
    for (int t = 0; t < 8; t++) {
      const int i = t * 4 + wave;
      const int idx = i * 64 + lane;
      const int row = idx >> 4;
      const int c = (idx & 15) ^ (row & 15);
      load16_lds(Bt + (size_t)(n0 + row) * 2048 + k0 + c * 8, &sB[i * 512]);
    }
    __syncthreads();
#pragma unroll
    for (int ks = 0; ks < 4; ks++) {
      const int cs = ((ks * 4 + quad) ^ l16) << 3;
      bf16x8 af[2], bfr[4];
#pragma unroll
      for (int i = 0; i < 2; i++)
        af[i] = *(const bf16x8*)&sA[(wm * 32 + i * 16 + l16) * 128 + cs];
#pragma unroll
      for (int i = 0; i < 4; i++)
        bfr[i] = *(const bf16x8*)&sB[(wn * 64 + i * 16 + l16) * 128 + cs];
#pragma unroll
      for (int mi = 0; mi < 2; mi++)
#pragma unroll
        for (int ni = 0; ni < 4; ni++)
          acc[mi][ni] = MFMA_BF16(af[mi], bfr[ni], acc[mi][ni]);
    }
  }

#pragma unroll
  for (int mi = 0; mi < 2; mi++) {
    const int row = m0 + wm * 32 + mi * 16 + quad * 4;
#pragma unroll
    for (int ni = 0; ni < 4; ni++) {
      const int col = n0 + wn * 64 + ni * 16 + l16;
#pragma unroll
      for (int r = 0; r < 4; r++) {
        Cout[(size_t)(row + r) * 2048 + col] = acc[mi][ni][r] + ob[col];
      }
    }
  }
}

// ------------------------------- launcher ----------------------------------
extern "C" void kernel_launch(void* const* d_in, const int* in_sizes, int n_in,
                              void* d_out, int out_size, void* d_ws, size_t ws_size,
                              hipStream_t stream) {
  (void)in_sizes; (void)n_in; (void)out_size; (void)ws_size;
  const float* hs = (const float*)d_in[0];
  const float* qw = (const float*)d_in[1];
  const float* qb = (const float*)d_in[2];
  const float* kw = (const float*)d_in[3];
  const float* kb = (const float*)d_in[4];
  const float* vw = (const float*)d_in[5];
  const float* vb = (const float*)d_in[6];
  const float* ow = (const float*)d_in[7];
  const float* ob = (const float*)d_in[8];
  const int* wsz = (const int*)d_in[9];

  char* w = (char*)d_ws;
  unsigned short* hsb  = (unsigned short*)(w + 0);          //  8 MB (S,HID) bf16
  unsigned short* wqkv = (unsigned short*)(w + 8388608);    // 24 MB (6144,2048) bf16
  unsigned short* owb  = (unsigned short*)(w + 33554432);   //  8 MB
  unsigned short* Qb_  = (unsigned short*)(w + 41943040);   //  8 MB (H,S,D)
  unsigned short* Kb_  = (unsigned short*)(w + 50331648);   //  8 MB (H,S,D)
  unsigned short* Vtb  = (unsigned short*)(w + 58720256);   //  8 MB (H,D,S)
  unsigned short* atb  = (unsigned short*)(w + 67108864);   //  8 MB (S,H*D)

  cvt_all<<<20480, 256, 0, stream>>>(
      (const float4*)hs, (const float4*)qw, (const float4*)kw, (const float4*)vw,
      (const float4*)ow,
      (ushort4*)hsb, (ushort4*)wqkv, (ushort4*)(wqkv + 4194304),
      (ushort4*)(wqkv + 8388608), (ushort4*)owb);

  gemm_qkv<<<dim3(24, 8), 512, 0, stream>>>(hsb, wqkv, qb, kb, vb, Qb_, Kb_, Vtb);
  attn_fwd<<<dim3(32, 16), 256, 0, stream>>>(Qb_, Kb_, Vtb, atb, wsz);
  gemm_o<<<dim3(16, 32), 256, 0, stream>>>(atb, owb, ob, (float*)d_out);
}

// Round 5
// 310.112 us; speedup vs baseline: 1.0254x; 1.0233x over previous
//
#include <hip/hip_runtime.h>
#include <hip/hip_bf16.h>
#include <stdint.h>
#include <stddef.h>

// ---------------------------------------------------------------------------
// RingAttentionLayer on MI355X (gfx950)
// R12: (1) gemm_qkv reverted to R9 (best measured, 100.5us; depth lever was
// null in R11, XCD swizzle toxic in R10). Added one-time tail vmcnt(0) at
// kt==31 (closes a paper race on the last tile's ks=1 slice) + trailing
// drain. (2) attn_fwd grid transposed: h = blockIdx.x so XCD b%8 sees only
// heads {x, x+8} -> per-XCD K/V working set = 4MB = one L2; K/V re-reads
// (536MB across the grid) served from home-XCD L2 instead of L3.
// gemm_o / cvt_all unchanged.
// ---------------------------------------------------------------------------

typedef __attribute__((ext_vector_type(8))) short bf16x8;   // 8 bf16 = 4 VGPRs
typedef __attribute__((ext_vector_type(4))) float f32x4;

#define MFMA_BF16(a, b, c) __builtin_amdgcn_mfma_f32_16x16x32_bf16((a), (b), (c), 0, 0, 0)

__device__ __forceinline__ void load16_lds(const void* g, void* l) {
  __builtin_amdgcn_global_load_lds((const __attribute__((address_space(1))) void*)g,
                                   (__attribute__((address_space(3))) void*)l,
                                   16, 0, 0);
}

__device__ __forceinline__ unsigned short f2bf(float x) {
  union { __hip_bfloat16 b; unsigned short u; } cv;
  cv.b = __float2bfloat16(x);
  return cv.u;
}

// ------------------------------- convert -----------------------------------
__global__ __launch_bounds__(256) void cvt_all(
    const float4* __restrict__ s0, const float4* __restrict__ s1,
    const float4* __restrict__ s2, const float4* __restrict__ s3,
    const float4* __restrict__ s4,
    ushort4* __restrict__ d0, ushort4* __restrict__ d1,
    ushort4* __restrict__ d2, ushort4* __restrict__ d3,
    ushort4* __restrict__ d4) {
  const int seg = blockIdx.x >> 12;
  const int i = ((blockIdx.x & 4095) << 8) + threadIdx.x;
  const float4* s = seg == 0 ? s0 : seg == 1 ? s1 : seg == 2 ? s2 : seg == 3 ? s3 : s4;
  ushort4* d = seg == 0 ? d0 : seg == 1 ? d1 : seg == 2 ? d2 : seg == 3 ? d3 : d4;
  float4 v = s[i];
  ushort4 o;
  o.x = f2bf(v.x); o.y = f2bf(v.y); o.z = f2bf(v.z); o.w = f2bf(v.w);
  d[i] = o;
}

// --------------------------- fused QKV GEMM --------------------------------
// C[2048 x 6144] = A[2048 x 2048] * Bt[6144 x 2048]^T, scatter-epilogue to
// Q(H,S,D) scaled, K(H,S,D), V(H,D,S). 256x256 tile, BK=64 (2 slices of 32),
// grid (24,8), 512 threads (8 waves, 2M x 4N).
// LDS slice layout: [128 pairs][8 pos][16B]; logical chunk c (c>>2 = row
// parity, c&3 = 8-col group) lives at pos = c ^ (pair & 7)  (R9, 0-conflict).
__global__ __launch_bounds__(512, 2) void gemm_qkv(
    const unsigned short* __restrict__ A, const unsigned short* __restrict__ Bt,
    const float* __restrict__ qb, const float* __restrict__ kb,
    const float* __restrict__ vb,
    unsigned short* __restrict__ Qo, unsigned short* __restrict__ Ko,
    unsigned short* __restrict__ Vt) {
  // [buf][ks][128 pairs * 64 ushort] = 16KB per slice; 64KB per matrix.
  __shared__ __align__(16) unsigned short sA[2][2][128 * 64];
  __shared__ __align__(16) unsigned short sB[2][2][128 * 64];
  const int tid = threadIdx.x;
  const int wave = tid >> 6, lane = tid & 63;
  const int quad = lane >> 4, l16 = lane & 15;
  const int wr = wave >> 2, wc = wave & 3;       // 2 M-waves x 4 N-waves
  const int m0 = blockIdx.y << 8, n0 = blockIdx.x << 8;

  f32x4 acc[8][4] = {};
  bf16x8 af[8], bf01[2], bf23[2];

  // ---- staging geometry (per wave: 2 units x 1024B per slice) ----
  // unit u = rr*8 + wave covers pairs u*8 .. u*8+7. Lane l -> pair_local
  // l>>3, pos l&7; stored logical chunk c = pos ^ (pair&7) = (l&7)^(l>>3).
  const int sc_ = (lane & 7) ^ (lane >> 3);
  const int srow16 = 2 * (lane >> 3) + (sc_ >> 2);  // row within 16-row unit
  const int scol8 = (sc_ & 3) * 8;                  // col elems within slice

  auto stageA = [&](int kt_, int ks_) {
    unsigned short* dst = &sA[kt_ & 1][ks_][wave * 512];
    const unsigned short* src =
        A + (size_t)(m0 + wave * 16 + srow16) * 2048 + kt_ * 64 + ks_ * 32 + scol8;
#pragma unroll
    for (int rr = 0; rr < 2; rr++)
      load16_lds(src + (size_t)rr * 128 * 2048, dst + rr * 4096);
  };
  auto stageB = [&](int kt_, int ks_) {
    unsigned short* dst = &sB[kt_ & 1][ks_][wave * 512];
    const unsigned short* src =
        Bt + (size_t)(n0 + wave * 16 + srow16) * 2048 + kt_ * 64 + ks_ * 32 + scol8;
#pragma unroll
    for (int rr = 0; rr < 2; rr++)
      load16_lds(src + (size_t)rr * 128 * 2048, dst + rr * 4096);
  };

  // ---- frag read addressing ----
  // row = X + l16 (X multiple of 16) -> pair = X/2 + (l16>>1), pair&7 = l16>>1,
  // chunk c = (l16&1)*4 + quad -> pos = c ^ (l16>>1) (lane-constant).
  const int hl = l16 >> 1;
  const int pos8 = ((((l16 & 1) << 2) + quad) ^ hl) << 3;   // ushort offset
  const int aoff = (wr * 64 + hl) * 64 + pos8;   // + mi*512 per mi
  const int boff = (wc * 32 + hl) * 64 + pos8;   // + nj*512 per nj

// one phase: quadrant (K-slice KS, N-frag pair NB..NB+1), 16 MFMA.
#define PHASE(KS, NB, BF, READ_A, STAGE_STMT, VM_STMT)                         \
  {                                                                            \
    const unsigned short* sAp = &sA[kt & 1][KS][aoff];                         \
    const unsigned short* sBp = &sB[kt & 1][KS][boff];                         \
    if (READ_A) {                                                              \
      _Pragma("unroll") for (int mi = 0; mi < 8; mi++)                         \
          af[mi] = *(const bf16x8*)(sAp + mi * 512);                           \
    }                                                                          \
    _Pragma("unroll") for (int j = 0; j < 2; j++)                              \
        BF[j] = *(const bf16x8*)(sBp + (NB + j) * 512);                        \
    STAGE_STMT;                                                                \
    __builtin_amdgcn_s_barrier();                                              \
    asm volatile("s_waitcnt lgkmcnt(0)" ::: "memory");                         \
    __builtin_amdgcn_s_setprio(1);                                             \
    _Pragma("unroll") for (int mi = 0; mi < 8; mi++) {                         \
      acc[mi][NB] = MFMA_BF16(af[mi], BF[0], acc[mi][NB]);                     \
      acc[mi][NB + 1] = MFMA_BF16(af[mi], BF[1], acc[mi][NB + 1]);             \
    }                                                                          \
    __builtin_amdgcn_s_setprio(0);                                             \
    VM_STMT;                                                                   \
    __builtin_amdgcn_s_barrier();                                              \
  }

  // prologue: tile 0 in read order Ak0, Bk0, Ak1, Bk1 (8 loads), then wait
  // for the first two units only (vmcnt(4) -> Ak0,Bk0 landed; Ak1,Bk1 fly).
  stageA(0, 0); stageB(0, 0); stageA(0, 1); stageB(0, 1);
  asm volatile("s_waitcnt vmcnt(4)" ::: "memory");
  __builtin_amdgcn_s_barrier();

  for (int kt = 0; kt < 32; kt++) {
    const bool pf = (kt < 31);
    // ph1: ks=0, ni 0-1; issue A-k0 of kt+1
    PHASE(0, 0, bf01, true,  { if (pf) stageA(kt + 1, 0); }, {});
    // ph2: ks=0, ni 2-3; issue B-k0; drain to 4 -> A-k1,B-k1 of kt landed
    // (they are the 4 oldest of the 8 outstanding in steady state).
    PHASE(0, 2, bf23, false, { if (pf) stageB(kt + 1, 0); },
          {
            asm volatile("s_waitcnt vmcnt(4)" ::: "memory");
            if (kt == 31)  // tail: only 4 outstanding here -> drain fully
              asm volatile("s_waitcnt vmcnt(0)" ::: "memory");
          });
    // ph3: ks=1, ni 0-1; issue A-k1 of kt+1
    PHASE(1, 0, bf01, true,  { if (pf) stageA(kt + 1, 1); }, {});
    // ph4: ks=1, ni 2-3; issue B-k1; drain to 4 -> A-k0,B-k0 of kt+1 landed
    PHASE(1, 2, bf23, false, { if (pf) stageB(kt + 1, 1); },
          { asm volatile("s_waitcnt vmcnt(4)" ::: "memory"); });
  }
#undef PHASE
  // no LDS-DMA may outlive the loop (defensive; all landed by kt=31 drain).
  asm volatile("s_waitcnt vmcnt(0)" ::: "memory");

  const float qscale = 0.088388347648318447f * 1.4426950408889634f;  // scale*log2e
#pragma unroll
  for (int mi = 0; mi < 8; mi++) {
    const int row = m0 + wr * 128 + mi * 16 + quad * 4;
#pragma unroll
    for (int ni = 0; ni < 4; ni++) {
      const int col = n0 + wc * 64 + ni * 16 + l16;
#pragma unroll
      for (int r = 0; r < 4; r++) {
        const float v = acc[mi][ni][r];
        const int rr = row + r;
        if (col < 2048) {
          const int hh = col >> 7, d = col & 127;
          Qo[((size_t)hh * 2048 + rr) * 128 + d] = f2bf((v + qb[col]) * qscale);
        } else if (col < 4096) {
          const int f = col - 2048;
          const int hh = f >> 7, d = f & 127;
          Ko[((size_t)hh * 2048 + rr) * 128 + d] = f2bf(v + kb[f]);
        } else {
          const int f = col - 4096;
          const int hh = f >> 7, d = f & 127;
          Vt[((size_t)hh * 128 + d) * 2048 + rr] = f2bf(v + vb[f]);  // (H,D,S)
        }
      }
    }
  }
}

// ------------------------------ attention ----------------------------------
// grid (16 heads, 32 qtiles) -- h on blockIdx.x so XCD b%8 sees only heads
// {x, x+8}: per-XCD K/V working set = 4MB = one L2; K/V re-reads come from
// the home XCD's L2 instead of L3. 512 blocks, block = 256 threads (4 waves),
// 72KB LDS -> 2 blocks/CU = 8 waves/CU. Each wave owns 16 q. K/V double-
// buffered; transposed-score softmax; dual accumulators with masked fork at
// kt==qt; in-register ring combine.
__global__ __launch_bounds__(256, 2) void attn_fwd(
    const unsigned short* __restrict__ Q, const unsigned short* __restrict__ K,
    const unsigned short* __restrict__ V,   // (H, D, S) transposed
    unsigned short* __restrict__ O,         // (S, H*D) bf16
    const int* __restrict__ wsp) {
  const int qt = blockIdx.y, h = blockIdx.x;   // R12: transposed for XCD affinity
  const int tid = threadIdx.x;
  const int wave = tid >> 6, lane = tid & 63;
  const int quad = lane >> 4, l16 = lane & 15;

  __shared__ __align__(16) unsigned short sK0[64 * 128];  // Q staged here first
  __shared__ __align__(16) unsigned short sK1[64 * 128];
  __shared__ __align__(16) unsigned short sV0[128 * 64];
  __shared__ __align__(16) unsigned short sV1[128 * 64];
  __shared__ __align__(16) unsigned short sP[4][16 * 64];

  const unsigned short* Qh = Q + (size_t)h * 2048 * 128;
  const unsigned short* Kh = K + (size_t)h * 2048 * 128;
  const unsigned short* Vh = V + (size_t)h * 128 * 2048;
  unsigned short* sPw = sP[wave];

  // stage Q tile [64][128] into sK0, chunk swizzle blk ^ (row&15)
  for (int c = wave; c < 16; c += 4) {
    const int rowc = lane >> 4;
    const int row = c * 4 + rowc;
    const int blk = (lane & 15) ^ (row & 15);
    load16_lds(Qh + (size_t)(qt * 64 + row) * 128 + blk * 8, &sK0[c * 512]);
  }
  __syncthreads();

  bf16x8 qf[4];
#pragma unroll
  for (int ds = 0; ds < 4; ds++)
    qf[ds] = *(const bf16x8*)&sK0[(wave * 16 + l16) * 128 + (((ds * 4 + quad) ^ l16) << 3)];
  __syncthreads();  // all waves hold Q frags before K0 overwrites sK0

  float m1 = -3.0e38f, l1 = 0.f, m2 = -3.0e38f, l2 = 0.f;
  f32x4 o1[8], o2[8];
#pragma unroll
  for (int j = 0; j < 8; j++) { o1[j] = f32x4{0.f, 0.f, 0.f, 0.f}; o2[j] = f32x4{0.f, 0.f, 0.f, 0.f}; }

  auto stageKV = [&](int kt, unsigned short* kDst, unsigned short* vDst) {
    const int k0 = kt << 6;
    for (int c = wave; c < 16; c += 4) {
      {  // K tile [64 k][128 d]
        const int rowc = lane >> 4;
        const int row = c * 4 + rowc;
        const int blk = (lane & 15) ^ (row & 15);
        load16_lds(Kh + (size_t)(k0 + row) * 128 + blk * 8, &kDst[c * 512]);
      }
      {  // V tile [128 d][64 k]
        const int rowc = lane >> 3;
        const int row = c * 8 + rowc;
        const int blk = (lane & 7) ^ (rowc & 7);
        load16_lds(Vh + (size_t)row * 2048 + k0 + blk * 8, &vDst[c * 512]);
      }
    }
  };

  auto softmax_update = [&](float& m, float& l, f32x4 (&o)[8],
                            const f32x4 (&stt)[4], bool masked, int k0) {
    const int qg = qt * 64 + wave * 16 + l16;  // this lane's q column
    float t[4][4];
    float mx = -3.0e38f;
#pragma unroll
    for (int ni = 0; ni < 4; ni++)
#pragma unroll
      for (int r = 0; r < 4; r++) {
        float v = stt[ni][r];
        if (masked && (k0 + ni * 16 + quad * 4 + r > qg)) v = -3.0e38f;
        t[ni][r] = v;
        mx = fmaxf(mx, v);
      }
    mx = fmaxf(mx, __shfl_xor(mx, 16));
    mx = fmaxf(mx, __shfl_xor(mx, 32));
    const float mn = fmaxf(m, mx);
    const float al = exp2f(m - mn);
    float rs = 0.f;
#pragma unroll
    for (int ni = 0; ni < 4; ni++) {
      union { unsigned short u[4]; uint2 v; } pk;
#pragma unroll
      for (int r = 0; r < 4; r++) {
        const float p = exp2f(t[ni][r] - mn);
        rs += p;
        pk.u[r] = f2bf(p);
      }
      const int off =
          l16 * 64 + (((ni * 2 + (quad >> 1)) ^ (l16 & 7)) << 3) + ((quad & 1) << 2);
      *(uint2*)&sPw[off] = pk.v;
    }
    rs += __shfl_xor(rs, 16);
    rs += __shfl_xor(rs, 32);
    const bool grew = !__all(mn == m);
    l = l * al + rs;
    m = mn;
    if (grew) {  // wave-uniform: skip o-rescale when no lane's max moved
#pragma unroll
      for (int r = 0; r < 4; r++) {
        const int src = (lane & 48) + quad * 4 + r;  // same quad, l16 = quad*4+r
        const float ab = __shfl(al, src);
#pragma unroll
        for (int j = 0; j < 8; j++) o[j][r] *= ab;
      }
    }
  };

  auto pv = [&](f32x4 (&o)[8], const unsigned short* vBuf) {
#pragma unroll
    for (int ks = 0; ks < 2; ks++) {
      const int cs = (((ks * 4 + quad) ^ (l16 & 7)) << 3);
      const bf16x8 pf = *(const bf16x8*)&sPw[l16 * 64 + cs];
#pragma unroll
      for (int j = 0; j < 8; j++) {
        const bf16x8 vf = *(const bf16x8*)&vBuf[(j * 16 + l16) * 64 + cs];
        o[j] = MFMA_BF16(pf, vf, o[j]);
      }
    }
  };

  auto compute_tile = [&](int kt, const unsigned short* kBuf,
                          const unsigned short* vBuf) {
    const int k0 = kt << 6;
    f32x4 st[4];
#pragma unroll
    for (int ni = 0; ni < 4; ni++) st[ni] = f32x4{0.f, 0.f, 0.f, 0.f};
#pragma unroll
    for (int ds = 0; ds < 4; ds++) {
#pragma unroll
      for (int ni = 0; ni < 4; ni++) {
        const bf16x8 kf =
            *(const bf16x8*)&kBuf[(ni * 16 + l16) * 128 + (((ds * 4 + quad) ^ l16) << 3)];
        st[ni] = MFMA_BF16(kf, qf[ds], st[ni]);
      }
    }

    if (kt == qt) {  // diagonal: fork masked stats, dual update
      m1 = m2; l1 = l2;
#pragma unroll
      for (int j = 0; j < 8; j++) o1[j] = o2[j];
      softmax_update(m1, l1, o1, st, true, k0);
      pv(o1, vBuf);
    }
    softmax_update(m2, l2, o2, st, false, k0);
    pv(o2, vBuf);
  };

  // pipelined K-loop: stage(kt+1) issues right after the barrier that
  // drained stage(kt); compute(kt) hides the latency.
  stageKV(0, sK0, sV0);
  for (int kt2 = 0; kt2 < 32; kt2 += 2) {
    __syncthreads();                       // drains stage(kt2) [buf0]
    if (kt2 + 1 < 32) stageKV(kt2 + 1, sK1, sV1);
    compute_tile(kt2, sK0, sV0);
    __syncthreads();                       // drains stage(kt2+1) [buf1]
    if (kt2 + 2 < 32) stageKV(kt2 + 2, sK0, sV0);
    compute_tile(kt2 + 1, sK1, sV1);
  }

  // in-register ring combine: 1x masked + (ws-1)x unmasked (log2 domain)
  const float fws = (float)(wsp[0] - 1);
  const float a = exp2f(m1 - m2);
  const float se = l1 * a + fws * l2;
  const float inv = 1.0f / (se + 1e-8f);
  const float f1 = (a / (l1 + 1e-8f)) * inv;
  const float f2 = (fws / (l2 + 1e-8f)) * inv;
#pragma unroll
  for (int r = 0; r < 4; r++) {
    const int src = (lane & 48) + quad * 4 + r;  // same quad, l16 = quad*4+r
    const float f1b = __shfl(f1, src);
    const float f2b = __shfl(f2, src);
    const int row = qt * 64 + wave * 16 + quad * 4 + r;
#pragma unroll
    for (int j = 0; j < 8; j++) {
      const float ov = o1[j][r] * f1b + o2[j][r] * f2b;
      O[(size_t)row * 2048 + h * 128 + j * 16 + l16] = f2bf(ov);
    }
  }
}

// ------------------------------ O-proj GEMM --------------------------------
// out[2048 x 2048] fp32 = attn[2048 x 2048]bf16 * ow[2048 x 2048]^T + ob
// 64x128 tile, BK=128 (16 iters), chunk-XOR swizzle on 16-chunk rows.
__global__ __launch_bounds__(256) void gemm_o(
    const unsigned short* __restrict__ A, const unsigned short* __restrict__ Bt,
    const float* __restrict__ ob, float* __restrict__ Cout) {
  __shared__ __align__(16) unsigned short sA[64 * 128];
  __shared__ __align__(16) unsigned short sB[128 * 128];
  const int tid = threadIdx.x;
  const int wave = tid >> 6, lane = tid & 63;
  const int quad = lane >> 4, l16 = lane & 15;
  const int wm = wave >> 1, wn = wave & 1;
  const int m0 = blockIdx.y << 6, n0 = blockIdx.x << 7;

  f32x4 acc[2][4] = {};

  for (int k0 = 0; k0 < 2048; k0 += 128) {
    __syncthreads();
#pragma unroll
    for (int t = 0; t < 4; t++) {
      const int i = t * 4 + wave;
      const int idx = i * 64 + lane;
      const int row = idx >> 4;
      const int c = (idx & 15) ^ (row & 15);
      load16_lds(A + (size_t)(m0 + row) * 2048 + k0 + c * 8, &sA[i * 512]);
    }
#pragma unroll
    for (int t = 0; t < 8; t++) {
      const int i = t * 4 + wave;
      const int idx = i * 64 + lane;
      const int row = idx >> 4;
      const int c = (idx & 15) ^ (row & 15);
      load16_lds(Bt + (size_t)(n0 + row) * 2048 + k0 + c * 8, &sB[i * 512]);
    }
    __syncthreads();
#pragma unroll
    for (int ks = 0; ks < 4; ks++) {
      const int cs = ((ks * 4 + quad) ^ l16) << 3;
      bf16x8 af[2], bfr[4];
#pragma unroll
      for (int i = 0; i < 2; i++)
        af[i] = *(const bf16x8*)&sA[(wm * 32 + i * 16 + l16) * 128 + cs];
#pragma unroll
      for (int i = 0; i < 4; i++)
        bfr[i] = *(const bf16x8*)&sB[(wn * 64 + i * 16 + l16) * 128 + cs];
#pragma unroll
      for (int mi = 0; mi < 2; mi++)
#pragma unroll
        for (int ni = 0; ni < 4; ni++)
          acc[mi][ni] = MFMA_BF16(af[mi], bfr[ni], acc[mi][ni]);
    }
  }

#pragma unroll
  for (int mi = 0; mi < 2; mi++) {
    const int row = m0 + wm * 32 + mi * 16 + quad * 4;
#pragma unroll
    for (int ni = 0; ni < 4; ni++) {
      const int col = n0 + wn * 64 + ni * 16 + l16;
#pragma unroll
      for (int r = 0; r < 4; r++) {
        Cout[(size_t)(row + r) * 2048 + col] = acc[mi][ni][r] + ob[col];
      }
    }
  }
}

// ------------------------------- launcher ----------------------------------
extern "C" void kernel_launch(void* const* d_in, const int* in_sizes, int n_in,
                              void* d_out, int out_size, void* d_ws, size_t ws_size,
                              hipStream_t stream) {
  (void)in_sizes; (void)n_in; (void)out_size; (void)ws_size;
  const float* hs = (const float*)d_in[0];
  const float* qw = (const float*)d_in[1];
  const float* qb = (const float*)d_in[2];
  const float* kw = (const float*)d_in[3];
  const float* kb = (const float*)d_in[4];
  const float* vw = (const float*)d_in[5];
  const float* vb = (const float*)d_in[6];
  const float* ow = (const float*)d_in[7];
  const float* ob = (const float*)d_in[8];
  const int* wsz = (const int*)d_in[9];

  char* w = (char*)d_ws;
  unsigned short* hsb  = (unsigned short*)(w + 0);          //  8 MB (S,HID) bf16
  unsigned short* wqkv = (unsigned short*)(w + 8388608);    // 24 MB (6144,2048) bf16
  unsigned short* owb  = (unsigned short*)(w + 33554432);   //  8 MB
  unsigned short* Qb_  = (unsigned short*)(w + 41943040);   //  8 MB (H,S,D)
  unsigned short* Kb_  = (unsigned short*)(w + 50331648);   //  8 MB (H,S,D)
  unsigned short* Vtb  = (unsigned short*)(w + 58720256);   //  8 MB (H,D,S)
  unsigned short* atb  = (unsigned short*)(w + 67108864);   //  8 MB (S,H*D)

  cvt_all<<<20480, 256, 0, stream>>>(
      (const float4*)hs, (const float4*)qw, (const float4*)kw, (const float4*)vw,
      (const float4*)ow,
      (ushort4*)hsb, (ushort4*)wqkv, (ushort4*)(wqkv + 4194304),
      (ushort4*)(wqkv + 8388608), (ushort4*)owb);

  gemm_qkv<<<dim3(24, 8), 512, 0, stream>>>(hsb, wqkv, qb, kb, vb, Qb_, Kb_, Vtb);
  attn_fwd<<<dim3(16, 32), 256, 0, stream>>>(Qb_, Kb_, Vtb, atb, wsz);
  gemm_o<<<dim3(16, 32), 256, 0, stream>>>(atb, owb, ob, (float*)d_out);
}